// Round 3
// baseline (1279.013 us; speedup 1.0000x reference)
//
#include <hip/hip_runtime.h>

#define F 256
#define NODE_BUDGET 200.0f
#define COS_EPS 1e-6f

// monotone float<->uint encoding for atomicMax over signed floats
__device__ __forceinline__ unsigned int encf(float f) {
    unsigned int u = __float_as_uint(f);
    return (u & 0x80000000u) ? ~u : (u | 0x80000000u);
}
__device__ __forceinline__ float decf(unsigned int u) {
    return (u & 0x80000000u) ? __uint_as_float(u & 0x7FFFFFFFu) : __uint_as_float(~u);
}

// Per-root precompute: g[b][f] = x_root*w_ego_root*w_ego_u, nr[b]=||x_root*w_ego_root||,
// sv[b]=x_root . w_layer_v, bscale[b]=budgets[b]/200
__global__ __launch_bounds__(256) void root_kernel(
    const float* __restrict__ x,
    const float* __restrict__ w_ego_root,
    const float* __restrict__ w_ego_u,
    const float* __restrict__ w_layer_v,
    const float* __restrict__ budgets,
    const int* __restrict__ batch_nodes,
    float* __restrict__ g, float* __restrict__ nr,
    float* __restrict__ sv, float* __restrict__ bscale)
{
    __shared__ float red[2][4];
    int b = blockIdx.x;
    int f = threadIdx.x;  // F == 256 == blockDim.x
    int root = batch_nodes[b];
    float xf = x[(size_t)root * F + f];
    float hr = xf * w_ego_root[f];
    g[(size_t)b * F + f] = hr * w_ego_u[f];
    float a = hr * hr;
    float c = xf * w_layer_v[f];
    #pragma unroll
    for (int off = 32; off; off >>= 1) {
        a += __shfl_xor(a, off);
        c += __shfl_xor(c, off);
    }
    int lane = f & 63, wv = f >> 6;
    if (lane == 0) { red[0][wv] = a; red[1][wv] = c; }
    __syncthreads();
    if (f == 0) {
        float as = red[0][0] + red[0][1] + red[0][2] + red[0][3];
        float cs = red[1][0] + red[1][1] + red[1][2] + red[1][3];
        nr[b] = sqrtf(as);
        sv[b] = cs;
        bscale[b] = budgets[b] * (1.0f / NODE_BUDGET);
    }
}

// agg[dst] += sv[src] over E edges
__global__ __launch_bounds__(256) void edge_kernel(
    const int* __restrict__ edge_src, const int* __restrict__ edge_dst,
    const float* __restrict__ sv, float* __restrict__ agg, int E)
{
    int i = blockIdx.x * 256 + threadIdx.x;
    int stride = gridDim.x * 256;
    for (; i < E; i += stride)
        atomicAdd(&agg[edge_dst[i]], sv[edge_src[i]]);
}

// One wave per candidate m: three F-length reductions over x[u_ids[m]]
__global__ __launch_bounds__(256) void cand_kernel(
    const float* __restrict__ x,
    const float* __restrict__ w_ego_u,
    const float* __restrict__ w_layer_u,
    const float* __restrict__ n_imp,
    const int* __restrict__ u_ids, const int* __restrict__ batch_ptr,
    const float* __restrict__ g, const float* __restrict__ nr,
    const float* __restrict__ bscale, const float* __restrict__ agg,
    float* __restrict__ p_out, unsigned int* __restrict__ pmax, int M)
{
    int gid = blockIdx.x * 256 + threadIdx.x;
    int m = gid >> 6;
    int lane = gid & 63;
    if (m >= M) return;
    int u = u_ids[m];
    int b = batch_ptr[m];
    // lane handles features [4*lane, 4*lane+4): 16B/lane * 64 lanes = full row
    float4 xs = ((const float4*)(x + (size_t)u * F))[lane];
    float4 gv = ((const float4*)(g + (size_t)b * F))[lane];   // L1/L2-hot (batch_ptr sorted)
    float4 wu = ((const float4*)w_ego_u)[lane];
    float4 wl = ((const float4*)w_layer_u)[lane];
    float d = xs.x * gv.x + xs.y * gv.y + xs.z * gv.z + xs.w * gv.w;
    float h0 = xs.x * wu.x, h1 = xs.y * wu.y, h2 = xs.z * wu.z, h3 = xs.w * wu.w;
    float n2 = h0 * h0 + h1 * h1 + h2 * h2 + h3 * h3;
    float s = xs.x * wl.x + xs.y * wl.y + xs.z * wl.z + xs.w * wl.w;
    #pragma unroll
    for (int off = 32; off; off >>= 1) {
        d  += __shfl_xor(d, off);
        n2 += __shfl_xor(n2, off);
        s  += __shfl_xor(s, off);
    }
    if (lane == 0) {
        float nu = sqrtf(n2);
        float ego = d / (fmaxf(nr[b], COS_EPS) * fmaxf(nu, COS_EPS));
        float layer = tanhf(agg[m] + s);
        float p = (0.5f * ego + 0.5f * layer) * n_imp[u] * bscale[b];
        p_out[m] = p;                      // stash p in the output buffer
        atomicMax(&pmax[b], encf(p));
    }
}

__global__ __launch_bounds__(256) void fin_kernel(
    const unsigned int* __restrict__ pmax,
    const int* __restrict__ batch_ptr, float* __restrict__ out, int M)
{
    int m = blockIdx.x * 256 + threadIdx.x;
    if (m >= M) return;
    float p = out[m];
    float pn = decf(pmax[batch_ptr[m]]);
    float v = p / pn + 1.0f;
    if (isnan(v)) v = 0.0f;
    else if (isinf(v)) v = 1.0f;
    v = fminf(fmaxf(v, 1e-5f), 1.0f);
    out[m] = v;
}

extern "C" void kernel_launch(void* const* d_in, const int* in_sizes, int n_in,
                              void* d_out, int out_size, void* d_ws, size_t ws_size,
                              hipStream_t stream) {
    const float* x          = (const float*)d_in[0];
    const float* w_ego_root = (const float*)d_in[1];
    const float* w_ego_u    = (const float*)d_in[2];
    const float* w_layer_v  = (const float*)d_in[3];
    const float* w_layer_u  = (const float*)d_in[4];
    const float* n_imp      = (const float*)d_in[5];
    const float* budgets    = (const float*)d_in[6];
    const int* batch_nodes = (const int*)d_in[7];
    const int* u_ids       = (const int*)d_in[8];
    const int* batch_ptr   = (const int*)d_in[9];
    const int* edge_src    = (const int*)d_in[10];
    const int* edge_dst    = (const int*)d_in[11];
    float* out = (float*)d_out;

    int B = in_sizes[7];
    int M = in_sizes[8];
    int E = in_sizes[10];

    float* ws = (float*)d_ws;
    size_t off = 0;
    float* agg = ws + off;                          off += (size_t)((M + 3) & ~3);
    unsigned int* pmax = (unsigned int*)(ws + off); off += (size_t)((B + 3) & ~3);
    size_t zero_bytes = off * sizeof(float);        // agg + pmax need zero-init
    float* g      = ws + off;                       off += (size_t)B * F;
    float* nr     = ws + off;                       off += (size_t)((B + 3) & ~3);
    float* sv     = ws + off;                       off += (size_t)((B + 3) & ~3);
    float* bscale = ws + off;                       off += (size_t)((B + 3) & ~3);

    hipMemsetAsync(d_ws, 0, zero_bytes, stream);

    root_kernel<<<B, 256, 0, stream>>>(x, w_ego_root, w_ego_u, w_layer_v,
                                       budgets, batch_nodes, g, nr, sv, bscale);
    edge_kernel<<<2048, 256, 0, stream>>>(edge_src, edge_dst, sv, agg, E);
    int cand_blocks = (M + 3) / 4;  // 4 waves per 256-thread block, 1 wave per candidate
    cand_kernel<<<cand_blocks, 256, 0, stream>>>(x, w_ego_u, w_layer_u, n_imp,
                                                 u_ids, batch_ptr, g, nr, bscale,
                                                 agg, out, pmax, M);
    fin_kernel<<<(M + 255) / 256, 256, 0, stream>>>(pmax, batch_ptr, out, M);
}

// Round 4
// 548.638 us; speedup vs baseline: 2.3313x; 2.3313x over previous
//
#include <hip/hip_runtime.h>

#define F 256
#define NODE_BUDGET 200.0f
#define COS_EPS 1e-6f

// Per-root precompute: g[b][f] = x_root*w_ego_root*w_ego_u, nr[b]=||x_root*w_ego_root||,
// sv[b]=x_root . w_layer_v, bscale[b]=budgets[b]/200
__global__ __launch_bounds__(256) void root_kernel(
    const float* __restrict__ x,
    const float* __restrict__ w_ego_root,
    const float* __restrict__ w_ego_u,
    const float* __restrict__ w_layer_v,
    const float* __restrict__ budgets,
    const int* __restrict__ batch_nodes,
    float* __restrict__ g, float* __restrict__ nr,
    float* __restrict__ sv, float* __restrict__ bscale)
{
    __shared__ float red[2][4];
    int b = blockIdx.x;
    int f = threadIdx.x;  // F == 256 == blockDim.x
    int root = batch_nodes[b];
    float xf = x[(size_t)root * F + f];
    float hr = xf * w_ego_root[f];
    g[(size_t)b * F + f] = hr * w_ego_u[f];
    float a = hr * hr;
    float c = xf * w_layer_v[f];
    #pragma unroll
    for (int off = 32; off; off >>= 1) {
        a += __shfl_xor(a, off);
        c += __shfl_xor(c, off);
    }
    int lane = f & 63, wv = f >> 6;
    if (lane == 0) { red[0][wv] = a; red[1][wv] = c; }
    __syncthreads();
    if (f == 0) {
        float as = red[0][0] + red[0][1] + red[0][2] + red[0][3];
        float cs = red[1][0] + red[1][1] + red[1][2] + red[1][3];
        nr[b] = sqrtf(as);
        sv[b] = cs;
        bscale[b] = budgets[b] * (1.0f / NODE_BUDGET);
    }
}

// agg[dst] += sv[src] over E edges (dst ~uniform over M=500k -> low contention)
__global__ __launch_bounds__(256) void edge_kernel(
    const int* __restrict__ edge_src, const int* __restrict__ edge_dst,
    const float* __restrict__ sv, float* __restrict__ agg, int E)
{
    int i = blockIdx.x * 256 + threadIdx.x;
    int stride = gridDim.x * 256;
    for (; i < E; i += stride)
        atomicAdd(&agg[edge_dst[i]], sv[edge_src[i]]);
}

// One wave per candidate m: three F-length reductions over x[u_ids[m]].
// NO atomics here: sorted batch_ptr made same-address atomicMax fully serial (R3: 950us).
__global__ __launch_bounds__(256) void cand_kernel(
    const float* __restrict__ x,
    const float* __restrict__ w_ego_u,
    const float* __restrict__ w_layer_u,
    const float* __restrict__ n_imp,
    const int* __restrict__ u_ids, const int* __restrict__ batch_ptr,
    const float* __restrict__ g, const float* __restrict__ nr,
    const float* __restrict__ bscale, const float* __restrict__ agg,
    float* __restrict__ p_out, int M)
{
    int gid = blockIdx.x * 256 + threadIdx.x;
    int m = gid >> 6;
    int lane = gid & 63;
    if (m >= M) return;
    int u = u_ids[m];
    int b = batch_ptr[m];
    // lane handles features [4*lane, 4*lane+4): 16B/lane * 64 lanes = full row
    float4 xs = ((const float4*)(x + (size_t)u * F))[lane];
    float4 gv = ((const float4*)(g + (size_t)b * F))[lane];   // L1/L2-hot (batch_ptr sorted)
    float4 wu = ((const float4*)w_ego_u)[lane];
    float4 wl = ((const float4*)w_layer_u)[lane];
    float d = xs.x * gv.x + xs.y * gv.y + xs.z * gv.z + xs.w * gv.w;
    float h0 = xs.x * wu.x, h1 = xs.y * wu.y, h2 = xs.z * wu.z, h3 = xs.w * wu.w;
    float n2 = h0 * h0 + h1 * h1 + h2 * h2 + h3 * h3;
    float s = xs.x * wl.x + xs.y * wl.y + xs.z * wl.z + xs.w * wl.w;
    #pragma unroll
    for (int off = 32; off; off >>= 1) {
        d  += __shfl_xor(d, off);
        n2 += __shfl_xor(n2, off);
        s  += __shfl_xor(s, off);
    }
    if (lane == 0) {
        float nu = sqrtf(n2);
        float ego = d / (fmaxf(nr[b], COS_EPS) * fmaxf(nu, COS_EPS));
        float layer = tanhf(agg[m] + s);
        float p = (0.5f * ego + 0.5f * layer) * n_imp[u] * bscale[b];
        p_out[m] = p;   // stash p in the output buffer; normalized by fin_kernel
    }
}

// Deterministic segment max: batch_ptr sorted -> contiguous segments.
// One block per b; binary-search bounds; block-stride max reduce.
__global__ __launch_bounds__(256) void segmax_kernel(
    const float* __restrict__ p, const int* __restrict__ batch_ptr,
    float* __restrict__ pmax, int M)
{
    int b = blockIdx.x;
    int lo = 0, hi = M;
    while (lo < hi) { int mid = (lo + hi) >> 1; if (batch_ptr[mid] < b) lo = mid + 1; else hi = mid; }
    int start = lo;
    hi = M;
    while (lo < hi) { int mid = (lo + hi) >> 1; if (batch_ptr[mid] <= b) lo = mid + 1; else hi = mid; }
    int end = lo;
    float mx = -INFINITY;
    for (int i = start + threadIdx.x; i < end; i += 256)
        mx = fmaxf(mx, p[i]);
    #pragma unroll
    for (int off = 32; off; off >>= 1)
        mx = fmaxf(mx, __shfl_xor(mx, off));
    __shared__ float red[4];
    int lane = threadIdx.x & 63, wv = threadIdx.x >> 6;
    if (lane == 0) red[wv] = mx;
    __syncthreads();
    if (threadIdx.x == 0)
        pmax[b] = fmaxf(fmaxf(red[0], red[1]), fmaxf(red[2], red[3]));
}

__global__ __launch_bounds__(256) void fin_kernel(
    const float* __restrict__ pmax,
    const int* __restrict__ batch_ptr, float* __restrict__ out, int M)
{
    int m = blockIdx.x * 256 + threadIdx.x;
    if (m >= M) return;
    float p = out[m];
    float pn = pmax[batch_ptr[m]];
    float v = p / pn + 1.0f;
    if (isnan(v)) v = 0.0f;
    else if (isinf(v)) v = 1.0f;
    v = fminf(fmaxf(v, 1e-5f), 1.0f);
    out[m] = v;
}

extern "C" void kernel_launch(void* const* d_in, const int* in_sizes, int n_in,
                              void* d_out, int out_size, void* d_ws, size_t ws_size,
                              hipStream_t stream) {
    const float* x          = (const float*)d_in[0];
    const float* w_ego_root = (const float*)d_in[1];
    const float* w_ego_u    = (const float*)d_in[2];
    const float* w_layer_v  = (const float*)d_in[3];
    const float* w_layer_u  = (const float*)d_in[4];
    const float* n_imp      = (const float*)d_in[5];
    const float* budgets    = (const float*)d_in[6];
    const int* batch_nodes = (const int*)d_in[7];
    const int* u_ids       = (const int*)d_in[8];
    const int* batch_ptr   = (const int*)d_in[9];
    const int* edge_src    = (const int*)d_in[10];
    const int* edge_dst    = (const int*)d_in[11];
    float* out = (float*)d_out;

    int B = in_sizes[7];
    int M = in_sizes[8];
    int E = in_sizes[10];

    float* ws = (float*)d_ws;
    size_t off = 0;
    float* agg = ws + off;                          off += (size_t)((M + 3) & ~3);
    size_t zero_bytes = off * sizeof(float);        // only agg needs zero-init
    float* pmax   = ws + off;                       off += (size_t)((B + 3) & ~3);
    float* g      = ws + off;                       off += (size_t)B * F;
    float* nr     = ws + off;                       off += (size_t)((B + 3) & ~3);
    float* sv     = ws + off;                       off += (size_t)((B + 3) & ~3);
    float* bscale = ws + off;                       off += (size_t)((B + 3) & ~3);

    hipMemsetAsync(d_ws, 0, zero_bytes, stream);

    root_kernel<<<B, 256, 0, stream>>>(x, w_ego_root, w_ego_u, w_layer_v,
                                       budgets, batch_nodes, g, nr, sv, bscale);
    edge_kernel<<<2048, 256, 0, stream>>>(edge_src, edge_dst, sv, agg, E);
    int cand_blocks = (M + 3) / 4;  // 4 waves per 256-thread block, 1 wave per candidate
    cand_kernel<<<cand_blocks, 256, 0, stream>>>(x, w_ego_u, w_layer_u, n_imp,
                                                 u_ids, batch_ptr, g, nr, bscale,
                                                 agg, out, M);
    segmax_kernel<<<B, 256, 0, stream>>>(out, batch_ptr, pmax, M);
    fin_kernel<<<(M + 255) / 256, 256, 0, stream>>>(pmax, batch_ptr, out, M);
}

// Round 5
// 487.558 us; speedup vs baseline: 2.6233x; 1.1253x over previous
//
#include <hip/hip_runtime.h>

#define F 256
#define NODE_BUDGET 200.0f
#define COS_EPS 1e-6f

// Per-root precompute: g[b][f] = x_root*w_ego_root*w_ego_u, nr[b]=||x_root*w_ego_root||,
// sv[b]=x_root . w_layer_v, bscale[b]=budgets[b]/200
__global__ __launch_bounds__(256) void root_kernel(
    const float* __restrict__ x,
    const float* __restrict__ w_ego_root,
    const float* __restrict__ w_ego_u,
    const float* __restrict__ w_layer_v,
    const float* __restrict__ budgets,
    const int* __restrict__ batch_nodes,
    float* __restrict__ g, float* __restrict__ nr,
    float* __restrict__ sv, float* __restrict__ bscale)
{
    __shared__ float red[2][4];
    int b = blockIdx.x;
    int f = threadIdx.x;  // F == 256 == blockDim.x
    int root = batch_nodes[b];
    float xf = x[(size_t)root * F + f];
    float hr = xf * w_ego_root[f];
    g[(size_t)b * F + f] = hr * w_ego_u[f];
    float a = hr * hr;
    float c = xf * w_layer_v[f];
    #pragma unroll
    for (int off = 32; off; off >>= 1) {
        a += __shfl_xor(a, off);
        c += __shfl_xor(c, off);
    }
    int lane = f & 63, wv = f >> 6;
    if (lane == 0) { red[0][wv] = a; red[1][wv] = c; }
    __syncthreads();
    if (f == 0) {
        float as = red[0][0] + red[0][1] + red[0][2] + red[0][3];
        float cs = red[1][0] + red[1][1] + red[1][2] + red[1][3];
        nr[b] = sqrtf(as);
        sv[b] = cs;
        bscale[b] = budgets[b] * (1.0f / NODE_BUDGET);
    }
}

// Per-node precompute over ALL N nodes (streaming, coalesced):
// nodetab[n] = { ||x_n*w_ego_u||, x_n . w_layer_u, n_imp[n], 0 }
__global__ __launch_bounds__(256) void nodes_kernel(
    const float* __restrict__ x,
    const float* __restrict__ w_ego_u,
    const float* __restrict__ w_layer_u,
    const float* __restrict__ n_imp,
    float4* __restrict__ nodetab, int N)
{
    int wv = (blockIdx.x * 256 + threadIdx.x) >> 6;   // one wave per node
    int lane = threadIdx.x & 63;
    if (wv >= N) return;
    const float4* xr = (const float4*)(x + (size_t)wv * F);
    float4 xv = xr[lane];
    float4 wu = ((const float4*)w_ego_u)[lane];
    float4 wl = ((const float4*)w_layer_u)[lane];
    float h0 = xv.x * wu.x, h1 = xv.y * wu.y, h2 = xv.z * wu.z, h3 = xv.w * wu.w;
    float a = h0 * h0 + h1 * h1 + h2 * h2 + h3 * h3;
    float s = xv.x * wl.x + xv.y * wl.y + xv.z * wl.z + xv.w * wl.w;
    #pragma unroll
    for (int off = 32; off; off >>= 1) {
        a += __shfl_xor(a, off);
        s += __shfl_xor(s, off);
    }
    if (lane == 0)
        nodetab[wv] = make_float4(sqrtf(a), s, n_imp[wv], 0.0f);
}

// agg[dst] += sv[src] over E edges (dst ~uniform over M=500k -> low contention)
__global__ __launch_bounds__(256) void edge_kernel(
    const int* __restrict__ edge_src, const int* __restrict__ edge_dst,
    const float* __restrict__ sv, float* __restrict__ agg, int E)
{
    int i = blockIdx.x * 256 + threadIdx.x;
    int stride = gridDim.x * 256;
    for (; i < E; i += stride)
        atomicAdd(&agg[edge_dst[i]], sv[edge_src[i]]);
}

// 16 lanes per candidate, 4 candidates per wave: only the dot x_u . g_b is
// reduced here; u-only terms come from nodetab. Purely gather-bound.
__global__ __launch_bounds__(256) void cand_kernel(
    const float* __restrict__ x,
    const int* __restrict__ u_ids, const int* __restrict__ batch_ptr,
    const float* __restrict__ g, const float* __restrict__ nr,
    const float* __restrict__ bscale, const float* __restrict__ agg,
    const float4* __restrict__ nodetab,
    float* __restrict__ p_out, int M)
{
    int tid = threadIdx.x;
    int lane = tid & 63;
    int sub = lane >> 4;         // which of 4 candidates in this wave
    int sl = lane & 15;          // sub-lane within candidate group
    int m = blockIdx.x * 16 + (tid >> 6) * 4 + sub;
    if (m >= M) return;
    int u = u_ids[m];
    int b = batch_ptr[m];
    const float4* xr = (const float4*)(x + (size_t)u * F);
    const float4* gr = (const float4*)(g + (size_t)b * F);  // L1-hot (sorted batch_ptr)
    float acc = 0.0f;
    #pragma unroll
    for (int p = 0; p < 4; ++p) {
        float4 xv = xr[p * 16 + sl];
        float4 gv = gr[p * 16 + sl];
        acc += xv.x * gv.x + xv.y * gv.y + xv.z * gv.z + xv.w * gv.w;
    }
    #pragma unroll
    for (int off = 8; off; off >>= 1)
        acc += __shfl_xor(acc, off);   // reduce within 16-lane group
    if (sl == 0) {
        float4 nv = nodetab[u];        // {nu, su, n_imp, _}
        float ego = acc / (fmaxf(nr[b], COS_EPS) * fmaxf(nv.x, COS_EPS));
        float layer = tanhf(agg[m] + nv.y);
        float p = (0.5f * ego + 0.5f * layer) * nv.z * bscale[b];
        p_out[m] = p;   // stash; seg_norm_kernel normalizes in place
    }
}

// Fused segment-max + normalize: batch_ptr sorted -> contiguous segments.
// One block per b; binary-search bounds; max-reduce; normalize in place.
__global__ __launch_bounds__(256) void seg_norm_kernel(
    const int* __restrict__ batch_ptr, float* __restrict__ out, int M)
{
    int b = blockIdx.x;
    int lo = 0, hi = M;
    while (lo < hi) { int mid = (lo + hi) >> 1; if (batch_ptr[mid] < b) lo = mid + 1; else hi = mid; }
    int start = lo;
    hi = M;
    while (lo < hi) { int mid = (lo + hi) >> 1; if (batch_ptr[mid] <= b) lo = mid + 1; else hi = mid; }
    int end = lo;
    float mx = -INFINITY;
    for (int i = start + threadIdx.x; i < end; i += 256)
        mx = fmaxf(mx, out[i]);
    #pragma unroll
    for (int off = 32; off; off >>= 1)
        mx = fmaxf(mx, __shfl_xor(mx, off));
    __shared__ float red[4];
    __shared__ float s_pn;
    int lane = threadIdx.x & 63, wv = threadIdx.x >> 6;
    if (lane == 0) red[wv] = mx;
    __syncthreads();
    if (threadIdx.x == 0)
        s_pn = fmaxf(fmaxf(red[0], red[1]), fmaxf(red[2], red[3]));
    __syncthreads();
    float pn = s_pn;
    for (int i = start + threadIdx.x; i < end; i += 256) {
        float v = out[i] / pn + 1.0f;
        if (isnan(v)) v = 0.0f;
        else if (isinf(v)) v = 1.0f;
        out[i] = fminf(fmaxf(v, 1e-5f), 1.0f);
    }
}

extern "C" void kernel_launch(void* const* d_in, const int* in_sizes, int n_in,
                              void* d_out, int out_size, void* d_ws, size_t ws_size,
                              hipStream_t stream) {
    const float* x          = (const float*)d_in[0];
    const float* w_ego_root = (const float*)d_in[1];
    const float* w_ego_u    = (const float*)d_in[2];
    const float* w_layer_v  = (const float*)d_in[3];
    const float* w_layer_u  = (const float*)d_in[4];
    const float* n_imp      = (const float*)d_in[5];
    const float* budgets    = (const float*)d_in[6];
    const int* batch_nodes = (const int*)d_in[7];
    const int* u_ids       = (const int*)d_in[8];
    const int* batch_ptr   = (const int*)d_in[9];
    const int* edge_src    = (const int*)d_in[10];
    const int* edge_dst    = (const int*)d_in[11];
    float* out = (float*)d_out;

    int N = in_sizes[5];
    int B = in_sizes[7];
    int M = in_sizes[8];
    int E = in_sizes[10];

    float* ws = (float*)d_ws;
    size_t off = 0;
    float* agg = ws + off;                          off += (size_t)((M + 3) & ~3);
    size_t zero_bytes = off * sizeof(float);        // only agg needs zero-init
    float* g       = ws + off;                      off += (size_t)B * F;
    float* nr      = ws + off;                      off += (size_t)((B + 3) & ~3);
    float* sv      = ws + off;                      off += (size_t)((B + 3) & ~3);
    float* bscale  = ws + off;                      off += (size_t)((B + 3) & ~3);
    float4* nodetab = (float4*)(ws + off);          off += (size_t)N * 4;

    hipMemsetAsync(d_ws, 0, zero_bytes, stream);

    root_kernel<<<B, 256, 0, stream>>>(x, w_ego_root, w_ego_u, w_layer_v,
                                       budgets, batch_nodes, g, nr, sv, bscale);
    nodes_kernel<<<(N + 3) / 4, 256, 0, stream>>>(x, w_ego_u, w_layer_u, n_imp,
                                                  nodetab, N);
    edge_kernel<<<2048, 256, 0, stream>>>(edge_src, edge_dst, sv, agg, E);
    cand_kernel<<<(M + 15) / 16, 256, 0, stream>>>(x, u_ids, batch_ptr, g, nr,
                                                   bscale, agg, nodetab, out, M);
    seg_norm_kernel<<<B, 256, 0, stream>>>(batch_ptr, out, M);
}